// Round 2
// baseline (693.666 us; speedup 1.0000x reference)
//
#include <hip/hip_runtime.h>
#include <hip/hip_bf16.h>

// Shapes: B=16, C=768, HW=4096.
#define BATCH 16
#define CDIM 768
#define NDIM 4096

typedef float  floatx4 __attribute__((ext_vector_type(4)));
typedef short  bf16x8  __attribute__((ext_vector_type(8)));

__device__ __forceinline__ short f2bf(float f) {
  unsigned u = __float_as_uint(f);
  unsigned r = (u + 0x7FFFu + ((u >> 16) & 1u)) >> 16;  // RNE
  return (short)r;
}

// async global->LDS, 16B per lane. LDS dest = wave-uniform base + lane*16.
__device__ __forceinline__ void gl_lds16(const short* g, short* l) {
  __builtin_amdgcn_global_load_lds(
      (const __attribute__((address_space(1))) unsigned int*)g,
      (__attribute__((address_space(3))) unsigned int*)l, 16, 0, 0);
}

// ---------------- kernel 1: fp32 -> bf16 elementwise ----------------
__global__ __launch_bounds__(256) void k_cvt(const float* __restrict__ x,
                                             short* __restrict__ xb) {
  size_t i = ((size_t)blockIdx.x * 256 + threadIdx.x) * 16;
  const floatx4* src = (const floatx4*)(x + i);
  floatx4 f0 = src[0], f1 = src[1], f2 = src[2], f3 = src[3];
  bf16x8 lo, hi;
#pragma unroll
  for (int j = 0; j < 4; j++) {
    lo[j]     = f2bf(f0[j]);
    lo[j + 4] = f2bf(f1[j]);
    hi[j]     = f2bf(f2[j]);
    hi[j + 4] = f2bf(f3[j]);
  }
  *(bf16x8*)(xb + i)     = lo;
  *(bf16x8*)(xb + i + 8) = hi;
}

// ---------------- kernel 2: tiled transpose fp32 -> bf16 ----------------
__global__ __launch_bounds__(256) void k_transpose(const float* __restrict__ X,
                                                   short* __restrict__ XT) {
  __shared__ __align__(16) short T[64][72];  // +8 pad
  int b = blockIdx.z;
  const float* Xb = X + (size_t)b * CDIM * NDIM;
  short* XTb = XT + (size_t)b * NDIM * CDIM;
  int r  = threadIdx.x >> 2;   // 0..63
  int cq = threadIdx.x & 3;    // 0..3 (16-col chunk)
  int gr  = blockIdx.y * 64 + r;         // c index
  int gc0 = blockIdx.x * 64 + cq * 16;   // n index base
  const floatx4* src = (const floatx4*)(Xb + (size_t)gr * NDIM + gc0);
  floatx4 f0 = src[0], f1 = src[1], f2 = src[2], f3 = src[3];
  bf16x8 lo, hi;
#pragma unroll
  for (int j = 0; j < 4; j++) {
    lo[j] = f2bf(f0[j]); lo[j + 4] = f2bf(f1[j]);
    hi[j] = f2bf(f2[j]); hi[j + 4] = f2bf(f3[j]);
  }
  *(bf16x8*)&T[r][cq * 16]     = lo;
  *(bf16x8*)&T[r][cq * 16 + 8] = hi;
  __syncthreads();
  bf16x8 o0, o1;
#pragma unroll
  for (int j = 0; j < 8; j++) o0[j] = T[cq * 16 + j][r];
#pragma unroll
  for (int j = 0; j < 8; j++) o1[j] = T[cq * 16 + 8 + j][r];
  short* dst = XTb + (size_t)(blockIdx.x * 64 + r) * CDIM + blockIdx.y * 64 + cq * 16;
  *(bf16x8*)dst       = o0;
  *(bf16x8*)(dst + 8) = o1;
}

// ---------------- kernel 3: bt-GEMM, 256x256 tile, BK=64, DMA, XCD-pinned --
// C[m][n] = scale * sum_k A[m][k] * Bt[n][k]   (per batch)
//
// NEW this round: wave tile 64x64 -> 128x128 (block 128^2 -> 256^2).
// R1 post-mortem: at 64x64 wave tiles the kernel is LDS-READ-BW bound:
// per CU per K-step, 192 KB of LDS traffic at the measured ~85 B/cyc b128
// ceiling = ~2250 cyc vs only ~1240 cyc of MFMA work -> MfmaUtil 21%.
// FLOP per LDS byte = tm*tn/(tm+tn): 32 at 64x64, 65.6 at 128x128.
// At 128x128/wave: MFMA = 4 waves x 128 x 4.85 ~ 2480 cyc/CU/K-step vs
// LDS reads 128 KB ~ 1540 cyc + 64 KB DMA writes ~ 510 cyc -> compute-bound.
// acc[8][8] floatx4 = 256 VGPR -> 1 wave/SIMD (launch_bounds(256,1), ILP
// replaces TLP; all 64 MFMA per ks are independent). LDS 139,264 B -> 1
// block/CU. Pipeline (counted vmcnt, proven R1) unchanged: vmcnt(16) =
// next tile's 16 loads stay in flight. GS=544 layout + fragment-read
// formula unchanged (bank behavior preserved).
template <int M, int N, int K, int TM, int TN, bool SCALE>
__global__ __launch_bounds__(256, 1) void k_gemm(const short* __restrict__ A,
                                                 const short* __restrict__ Bt,
                                                 float* __restrict__ C,
                                                 const float* __restrict__ gamma) {
  constexpr int GS = 544;   // shorts per 8-row group (1024 B + 64 B pad)
  constexpr int PB = TM * TN;
  constexpr int NT = K / 64;          // >= 12 for both instantiations
  __shared__ __align__(16) short Al[2][32 * GS];   // 256 rows x 64 K, dbuf
  __shared__ __align__(16) short Bl[2][32 * GS];

  int xcd = blockIdx.x;                 // 0..7
  int y   = blockIdx.y;                 // 0..2*PB-1
  int b   = xcd + 8 * (y / PB);         // batch pinned to this XCD
  int r   = y % PB;
  int tm  = r % TM;
  int tn  = r / TM;

  const short* Ab = A  + (size_t)b * M * K;
  const short* Bb = Bt + (size_t)b * N * K;
  float* Cb = C + (size_t)b * M * N;

  int tid  = threadIdx.x;
  int lane = tid & 63;
  int wave = tid >> 6;
  int wm = (wave >> 1) * 128;           // wave tile: 128x128
  int wn = (wave & 1) * 128;

  // DMA: wave covers rows [wave*64, +64) = groups [wave*8, +8), 8 issues
  // per operand per tile (16 total per wave per K-tile).
  int lr = lane >> 3;    // row within 8-row issue
  int lc = lane & 7;     // 16B chunk within row
  const short* ga = Ab + (size_t)(tm * 256 + wave * 64 + lr) * K + lc * 8;
  const short* gb = Bb + (size_t)(tn * 256 + wave * 64 + lr) * K + lc * 8;
  int lofs = wave * 8 * GS;

  // stage one 64-wide K-tile into buffer `buf`; advances ga/gb by 64.
  auto stage = [&](int buf) {
#pragma unroll
    for (int j = 0; j < 8; j++)
      gl_lds16(ga + (size_t)j * 8 * K, &Al[buf][lofs + j * GS]);
#pragma unroll
    for (int j = 0; j < 8; j++)
      gl_lds16(gb + (size_t)j * 8 * K, &Bl[buf][lofs + j * GS]);
    ga += 64; gb += 64;
  };

  floatx4 acc[8][8] = {};
  int row = lane & 15, quad = lane >> 4;

  stage(0);   // tile 0 -> buf0
  stage(1);   // tile 1 -> buf1   (32 loads outstanding per wave)

  for (int t = 0; t < NT; ++t) {
    int buf = t & 1;
    // Wait for OWN tile-t loads (oldest 16). Tile t+1's 16 stay in flight,
    // except on the last iteration where nothing is behind -> vmcnt(0).
    if (t == NT - 1) asm volatile("s_waitcnt vmcnt(0)" ::: "memory");
    else             asm volatile("s_waitcnt vmcnt(16)" ::: "memory");
    __builtin_amdgcn_s_barrier();        // ALL waves' tile-t loads landed
    asm volatile("" ::: "memory");       // no ds_read hoisted above barrier

#pragma unroll
    for (int ks = 0; ks < 2; ks++) {
      bf16x8 af[8], bfv[8];
#pragma unroll
      for (int i = 0; i < 8; i++) {
        int R = wm + i * 16 + row;
        af[i] = *(const bf16x8*)&Al[buf][(R >> 3) * GS + (R & 7) * 64 + (ks * 4 + quad) * 8];
      }
#pragma unroll
      for (int i = 0; i < 8; i++) {
        int R = wn + i * 16 + row;
        bfv[i] = *(const bf16x8*)&Bl[buf][(R >> 3) * GS + (R & 7) * 64 + (ks * 4 + quad) * 8];
      }
#pragma unroll
      for (int i = 0; i < 8; i++)
#pragma unroll
        for (int j = 0; j < 8; j++)
          acc[i][j] = __builtin_amdgcn_mfma_f32_16x16x32_bf16(af[i], bfv[j], acc[i][j], 0, 0, 0);
    }

    asm volatile("" ::: "memory");       // no memory op crosses downward
    __builtin_amdgcn_s_barrier();        // all waves done reading buf[t&1]
    asm volatile("" ::: "memory");       // stage not hoisted above barrier
    if (t + 2 < NT) stage(buf);          // tile t+2 overwrites buf[t&1]
  }

  float g = SCALE ? gamma[0] : 1.0f;
  int col = lane & 15, rq = (lane >> 4) * 4;  // C/D: col=lane&15, row=quad*4+reg
#pragma unroll
  for (int i = 0; i < 8; i++)
#pragma unroll
    for (int j = 0; j < 8; j++)
#pragma unroll
      for (int rr = 0; rr < 4; rr++) {
        int m = tm * 256 + wm + i * 16 + rq + rr;
        int n = tn * 256 + wn + j * 16 + col;
        Cb[(size_t)m * N + n] = g * acc[i][j][rr];
      }
}

// ---------------- kernel 4: row softmax fp32 -> bf16 ----------------
__global__ __launch_bounds__(256) void k_softmax(const float* __restrict__ S,
                                                 short* __restrict__ P) {
  size_t row = blockIdx.x;
  const float* s = S + row * CDIM;
  short* p = P + row * CDIM;
  int tid = threadIdx.x;
  float v0 = s[tid], v1 = s[tid + 256], v2 = s[tid + 512];
  float m = fmaxf(fmaxf(v0, v1), v2);
#pragma unroll
  for (int o = 32; o; o >>= 1) m = fmaxf(m, __shfl_xor(m, o, 64));
  __shared__ float rmax[4], rsum[4];
  if ((tid & 63) == 0) rmax[tid >> 6] = m;
  __syncthreads();
  m = fmaxf(fmaxf(rmax[0], rmax[1]), fmaxf(rmax[2], rmax[3]));
  float e0 = __expf(v0 - m), e1 = __expf(v1 - m), e2 = __expf(v2 - m);
  float su = e0 + e1 + e2;
#pragma unroll
  for (int o = 32; o; o >>= 1) su += __shfl_xor(su, o, 64);
  if ((tid & 63) == 0) rsum[tid >> 6] = su;
  __syncthreads();
  float inv = 1.0f / (rsum[0] + rsum[1] + rsum[2] + rsum[3]);
  p[tid]       = f2bf(e0 * inv);
  p[tid + 256] = f2bf(e1 * inv);
  p[tid + 512] = f2bf(e2 * inv);
}

extern "C" void kernel_launch(void* const* d_in, const int* in_sizes, int n_in,
                              void* d_out, int out_size, void* d_ws, size_t ws_size,
                              hipStream_t stream) {
  const float* x     = (const float*)d_in[0];
  const float* gamma = (const float*)d_in[1];
  float* out = (float*)d_out;

  // workspace layout (150 MiB), proven in R1/R3/R4:
  //   [0, 100663296)         : Xb bf16 (phase 1) / XT bf16 (phase 2)
  //   [100663296, +37748736) : S fp32 [16][768][768]
  //   [+, +18874368)         : P bf16 [16][768][768]
  char* ws = (char*)d_ws;
  short* Xb = (short*)ws;
  float* S  = (float*)(ws + 100663296);
  short* P  = (short*)(ws + 100663296 + 37748736);

  // 1) X -> bf16 (row-major)
  {
    size_t total = (size_t)BATCH * CDIM * NDIM;  // 50331648
    k_cvt<<<(int)(total / (256 * 16)), 256, 0, stream>>>(x, Xb);
  }
  // 2) S = Xb * Xb^T  (M=N=768, K=4096), 256^2 tiles: 8 x 18 blocks
  k_gemm<CDIM, CDIM, NDIM, 3, 3, false>
      <<<dim3(8, 2 * 3 * 3, 1), 256, 0, stream>>>(Xb, Xb, S, nullptr);
  // 3) P = softmax_rows(S), bf16
  k_softmax<<<BATCH * CDIM, 256, 0, stream>>>(S, P);
  // 4) XT = transpose(X) in bf16 (overwrites Xb region; Xb dead after step 2)
  k_transpose<<<dim3(NDIM / 64, CDIM / 64, BATCH), 256, 0, stream>>>(x, Xb);
  // 5) out = gamma * (P * XT^T)  (M=768, N=4096, K=768), 256^2 tiles: 8 x 96
  k_gemm<CDIM, NDIM, CDIM, 3, 16, true>
      <<<dim3(8, 2 * 3 * 16, 1), 256, 0, stream>>>(P, Xb, out, gamma);
}

// Round 3
// 622.968 us; speedup vs baseline: 1.1135x; 1.1135x over previous
//
#include <hip/hip_runtime.h>
#include <hip/hip_bf16.h>

// Shapes: B=16, C=768, HW=4096.
#define BATCH 16
#define CDIM 768
#define NDIM 4096

typedef float  floatx4 __attribute__((ext_vector_type(4)));
typedef short  bf16x8  __attribute__((ext_vector_type(8)));

__device__ __forceinline__ short f2bf(float f) {
  unsigned u = __float_as_uint(f);
  unsigned r = (u + 0x7FFFu + ((u >> 16) & 1u)) >> 16;  // RNE
  return (short)r;
}

// async global->LDS, 16B per lane. LDS dest = wave-uniform base + lane*16.
__device__ __forceinline__ void gl_lds16(const short* g, short* l) {
  __builtin_amdgcn_global_load_lds(
      (const __attribute__((address_space(1))) unsigned int*)g,
      (__attribute__((address_space(3))) unsigned int*)l, 16, 0, 0);
}

// ---------------- kernel 1: fp32 -> bf16 elementwise ----------------
__global__ __launch_bounds__(256) void k_cvt(const float* __restrict__ x,
                                             short* __restrict__ xb) {
  size_t i = ((size_t)blockIdx.x * 256 + threadIdx.x) * 16;
  const floatx4* src = (const floatx4*)(x + i);
  floatx4 f0 = src[0], f1 = src[1], f2 = src[2], f3 = src[3];
  bf16x8 lo, hi;
#pragma unroll
  for (int j = 0; j < 4; j++) {
    lo[j]     = f2bf(f0[j]);
    lo[j + 4] = f2bf(f1[j]);
    hi[j]     = f2bf(f2[j]);
    hi[j + 4] = f2bf(f3[j]);
  }
  *(bf16x8*)(xb + i)     = lo;
  *(bf16x8*)(xb + i + 8) = hi;
}

// ---------------- kernel 2: tiled transpose fp32 -> bf16 ----------------
__global__ __launch_bounds__(256) void k_transpose(const float* __restrict__ X,
                                                   short* __restrict__ XT) {
  __shared__ __align__(16) short T[64][72];  // +8 pad
  int b = blockIdx.z;
  const float* Xb = X + (size_t)b * CDIM * NDIM;
  short* XTb = XT + (size_t)b * NDIM * CDIM;
  int r  = threadIdx.x >> 2;   // 0..63
  int cq = threadIdx.x & 3;    // 0..3 (16-col chunk)
  int gr  = blockIdx.y * 64 + r;         // c index
  int gc0 = blockIdx.x * 64 + cq * 16;   // n index base
  const floatx4* src = (const floatx4*)(Xb + (size_t)gr * NDIM + gc0);
  floatx4 f0 = src[0], f1 = src[1], f2 = src[2], f3 = src[3];
  bf16x8 lo, hi;
#pragma unroll
  for (int j = 0; j < 4; j++) {
    lo[j] = f2bf(f0[j]); lo[j + 4] = f2bf(f1[j]);
    hi[j] = f2bf(f2[j]); hi[j + 4] = f2bf(f3[j]);
  }
  *(bf16x8*)&T[r][cq * 16]     = lo;
  *(bf16x8*)&T[r][cq * 16 + 8] = hi;
  __syncthreads();
  bf16x8 o0, o1;
#pragma unroll
  for (int j = 0; j < 8; j++) o0[j] = T[cq * 16 + j][r];
#pragma unroll
  for (int j = 0; j < 8; j++) o1[j] = T[cq * 16 + 8 + j][r];
  short* dst = XTb + (size_t)(blockIdx.x * 64 + r) * CDIM + blockIdx.y * 64 + cq * 16;
  *(bf16x8*)dst       = o0;
  *(bf16x8*)(dst + 8) = o1;
}

// ---------------- kernel 3: bt-GEMM, 256x256 tile, 8 waves, BK=64 ----------
// C[m][n] = scale * sum_k A[m][k] * Bt[n][k]   (per batch)
//
// R2 post-mortem: 256^2 with 4 waves = 1 wave/SIMD -> zero TLP, every
// ds_read->MFMA dep and barrier fully exposed -> 16.6% MfmaUtil. Fix: keep
// the 256^2 tile (halved FETCH_SIZE + bank conflicts) but use 8 WAVES
// (512 thr), wave tile 128x64, acc[8][4] = 128 VGPR -> 2 waves/SIMD
// (launch_bounds(512,2) caps allocator at 256 VGPR, no spill).
// Per K64-tile per CU: MFMA = 512 x 4.85 ~ 2480 cyc vs LDS ~ 1000 cyc and
// stage lead ~ 2 compute-tiles (~2500 cyc >> 900-cyc HBM) -> compute-
// dominant with real TLP. Pipeline (R1-verified): double-buffer, stage(t+2)
// after the read-completion barrier, counted vmcnt (8 issues/wave/tile ->
// vmcnt(8) leaves next tile's loads in flight; never drain mid-loop).
// GS=544 layout + fragment-read formula unchanged (conflicts at b128 floor).
template <int M, int N, int K, int TM, int TN, bool SCALE>
__global__ __launch_bounds__(512, 2) void k_gemm(const short* __restrict__ A,
                                                 const short* __restrict__ Bt,
                                                 float* __restrict__ C,
                                                 const float* __restrict__ gamma) {
  constexpr int GS = 544;   // shorts per 8-row group (1024 B + 64 B pad)
  constexpr int PB = TM * TN;
  constexpr int NT = K / 64;          // >= 12 for both instantiations
  __shared__ __align__(16) short Al[2][32 * GS];   // 256 rows x 64 K, dbuf
  __shared__ __align__(16) short Bl[2][32 * GS];

  int xcd = blockIdx.x;                 // 0..7
  int y   = blockIdx.y;                 // 0..2*PB-1
  int b   = xcd + 8 * (y / PB);         // batch pinned to this XCD
  int r   = y % PB;
  int tm  = r % TM;
  int tn  = r / TM;

  const short* Ab = A  + (size_t)b * M * K;
  const short* Bb = Bt + (size_t)b * N * K;
  float* Cb = C + (size_t)b * M * N;

  int tid  = threadIdx.x;
  int lane = tid & 63;
  int wave = tid >> 6;                  // 0..7
  int wm = (wave >> 2) * 128;           // wave tile: 128 (m) x 64 (n)
  int wn = (wave & 3) * 64;

  // DMA: wave covers rows [wave*32, +32) = groups [wave*4, +4), 4 issues
  // per operand per K-tile (8 total per wave per tile).
  int lr = lane >> 3;    // row within 8-row issue
  int lc = lane & 7;     // 16B chunk within row
  const short* ga = Ab + (size_t)(tm * 256 + wave * 32 + lr) * K + lc * 8;
  const short* gb = Bb + (size_t)(tn * 256 + wave * 32 + lr) * K + lc * 8;
  int lofs = wave * 4 * GS;

  // stage one 64-wide K-tile into buffer `buf`; advances ga/gb by 64.
  auto stage = [&](int buf) {
#pragma unroll
    for (int j = 0; j < 4; j++)
      gl_lds16(ga + (size_t)j * 8 * K, &Al[buf][lofs + j * GS]);
#pragma unroll
    for (int j = 0; j < 4; j++)
      gl_lds16(gb + (size_t)j * 8 * K, &Bl[buf][lofs + j * GS]);
    ga += 64; gb += 64;
  };

  floatx4 acc[8][4] = {};
  int row = lane & 15, quad = lane >> 4;

  stage(0);   // tile 0 -> buf0
  stage(1);   // tile 1 -> buf1   (16 loads outstanding per wave)

  for (int t = 0; t < NT; ++t) {
    int buf = t & 1;
    // Wait for OWN tile-t loads (oldest 8). Tile t+1's 8 stay in flight,
    // except on the last iteration where nothing is behind -> vmcnt(0).
    if (t == NT - 1) asm volatile("s_waitcnt vmcnt(0)" ::: "memory");
    else             asm volatile("s_waitcnt vmcnt(8)" ::: "memory");
    __builtin_amdgcn_s_barrier();        // ALL waves' tile-t loads landed
    asm volatile("" ::: "memory");       // no ds_read hoisted above barrier

#pragma unroll
    for (int ks = 0; ks < 2; ks++) {
      bf16x8 af[8], bfv[4];
#pragma unroll
      for (int i = 0; i < 8; i++) {
        int R = wm + i * 16 + row;
        af[i] = *(const bf16x8*)&Al[buf][(R >> 3) * GS + (R & 7) * 64 + (ks * 4 + quad) * 8];
      }
#pragma unroll
      for (int j = 0; j < 4; j++) {
        int R = wn + j * 16 + row;
        bfv[j] = *(const bf16x8*)&Bl[buf][(R >> 3) * GS + (R & 7) * 64 + (ks * 4 + quad) * 8];
      }
#pragma unroll
      for (int i = 0; i < 8; i++)
#pragma unroll
        for (int j = 0; j < 4; j++)
          acc[i][j] = __builtin_amdgcn_mfma_f32_16x16x32_bf16(af[i], bfv[j], acc[i][j], 0, 0, 0);
    }

    asm volatile("" ::: "memory");       // no memory op crosses downward
    __builtin_amdgcn_s_barrier();        // all waves done reading buf[t&1]
    asm volatile("" ::: "memory");       // stage not hoisted above barrier
    if (t + 2 < NT) stage(buf);          // tile t+2 overwrites buf[t&1]
  }

  float g = SCALE ? gamma[0] : 1.0f;
  int col = lane & 15, rq = (lane >> 4) * 4;  // C/D: col=lane&15, row=quad*4+reg
#pragma unroll
  for (int i = 0; i < 8; i++)
#pragma unroll
    for (int j = 0; j < 4; j++)
#pragma unroll
      for (int rr = 0; rr < 4; rr++) {
        int m = tm * 256 + wm + i * 16 + rq + rr;
        int n = tn * 256 + wn + j * 16 + col;
        Cb[(size_t)m * N + n] = g * acc[i][j][rr];
      }
}

// ---------------- kernel 4: row softmax fp32 -> bf16 ----------------
__global__ __launch_bounds__(256) void k_softmax(const float* __restrict__ S,
                                                 short* __restrict__ P) {
  size_t row = blockIdx.x;
  const float* s = S + row * CDIM;
  short* p = P + row * CDIM;
  int tid = threadIdx.x;
  float v0 = s[tid], v1 = s[tid + 256], v2 = s[tid + 512];
  float m = fmaxf(fmaxf(v0, v1), v2);
#pragma unroll
  for (int o = 32; o; o >>= 1) m = fmaxf(m, __shfl_xor(m, o, 64));
  __shared__ float rmax[4], rsum[4];
  if ((tid & 63) == 0) rmax[tid >> 6] = m;
  __syncthreads();
  m = fmaxf(fmaxf(rmax[0], rmax[1]), fmaxf(rmax[2], rmax[3]));
  float e0 = __expf(v0 - m), e1 = __expf(v1 - m), e2 = __expf(v2 - m);
  float su = e0 + e1 + e2;
#pragma unroll
  for (int o = 32; o; o >>= 1) su += __shfl_xor(su, o, 64);
  if ((tid & 63) == 0) rsum[tid >> 6] = su;
  __syncthreads();
  float inv = 1.0f / (rsum[0] + rsum[1] + rsum[2] + rsum[3]);
  p[tid]       = f2bf(e0 * inv);
  p[tid + 256] = f2bf(e1 * inv);
  p[tid + 512] = f2bf(e2 * inv);
}

extern "C" void kernel_launch(void* const* d_in, const int* in_sizes, int n_in,
                              void* d_out, int out_size, void* d_ws, size_t ws_size,
                              hipStream_t stream) {
  const float* x     = (const float*)d_in[0];
  const float* gamma = (const float*)d_in[1];
  float* out = (float*)d_out;

  // workspace layout (150 MiB), proven in R1/R3/R4:
  //   [0, 100663296)         : Xb bf16 (phase 1) / XT bf16 (phase 2)
  //   [100663296, +37748736) : S fp32 [16][768][768]
  //   [+, +18874368)         : P bf16 [16][768][768]
  char* ws = (char*)d_ws;
  short* Xb = (short*)ws;
  float* S  = (float*)(ws + 100663296);
  short* P  = (short*)(ws + 100663296 + 37748736);

  // 1) X -> bf16 (row-major)
  {
    size_t total = (size_t)BATCH * CDIM * NDIM;  // 50331648
    k_cvt<<<(int)(total / (256 * 16)), 256, 0, stream>>>(x, Xb);
  }
  // 2) S = Xb * Xb^T  (M=N=768, K=4096), 256^2 tiles: 8 x 18 blocks
  k_gemm<CDIM, CDIM, NDIM, 3, 3, false>
      <<<dim3(8, 2 * 3 * 3, 1), 512, 0, stream>>>(Xb, Xb, S, nullptr);
  // 3) P = softmax_rows(S), bf16
  k_softmax<<<BATCH * CDIM, 256, 0, stream>>>(S, P);
  // 4) XT = transpose(X) in bf16 (overwrites Xb region; Xb dead after step 2)
  k_transpose<<<dim3(NDIM / 64, CDIM / 64, BATCH), 256, 0, stream>>>(x, Xb);
  // 5) out = gamma * (P * XT^T)  (M=768, N=4096, K=768), 256^2 tiles: 8 x 96
  k_gemm<CDIM, NDIM, CDIM, 3, 16, true>
      <<<dim3(8, 2 * 3 * 16, 1), 512, 0, stream>>>(P, Xb, out, gamma);
}